// Round 6
// baseline (1365.214 us; speedup 1.0000x reference)
//
#include <hip/hip_runtime.h>
#include <stdint.h>

typedef __fp16 half2v __attribute__((ext_vector_type(2)));

#define Lr   512
#define Br   128
#define DINr 256
#define DHr  512

__device__ __forceinline__ float fdot2(half2v a, half2v b, float c) {
    return __builtin_amdgcn_fdot2(a, b, c, false);
}
__device__ __forceinline__ uint32_t pk_u32(float lo, float hi) {
    half2v h = __builtin_amdgcn_cvt_pkrtz(lo, hi);
    return __builtin_bit_cast(uint32_t, h);
}
__device__ __forceinline__ half2v u32_h2(uint32_t u) {
    return __builtin_bit_cast(half2v, u);
}

// ---------------------------------------------------------------------------
// Kernel A: xp[t,b,:] = x[t,b,:] @ Wx + bx   written into d_out (reused as
// xp buffer; kernel B reads xp[t] then overwrites the same slice with h[t]).
// Grid (256 row-tiles, 2 col-halves) x 256 threads. Wx column in regs (f16
// pairs), x rows staged through LDS as packed f16 pairs (broadcast reads).
// ---------------------------------------------------------------------------
__global__ __launch_bounds__(256)
void xp_kernel(const float* __restrict__ x, const float* __restrict__ Wx,
               const float* __restrict__ bx, float* __restrict__ out)
{
    const int tid     = threadIdx.x;
    const int rowbase = blockIdx.x * 256;          // 256 tiles * 256 rows = 65536
    const int col     = blockIdx.y * 256 + tid;    // 0..511

    half2v wx[128];
    #pragma unroll
    for (int q = 0; q < 128; ++q) {
        float w0 = Wx[(size_t)(2*q)   * DHr + col];
        float w1 = Wx[(size_t)(2*q+1) * DHr + col];
        wx[q] = __builtin_amdgcn_cvt_pkrtz(w0, w1);
    }
    const float bxv = bx[col];

    __shared__ __align__(16) uint32_t xstage[8][128];

    const int m = tid & 127;   // pair index within row
    const int g = tid >> 7;    // row group (0/1)

    for (int rc = 0; rc < 32; ++rc) {
        const int r0 = rowbase + rc * 8;
        __syncthreads();
        #pragma unroll
        for (int rr = 0; rr < 4; ++rr) {
            const int r = g * 4 + rr;
            const float2 xv = *(const float2*)(x + (size_t)(r0 + r) * DINr + 2 * m);
            xstage[r][m] = pk_u32(xv.x, xv.y);
        }
        __syncthreads();
        #pragma unroll
        for (int r = 0; r < 8; ++r) {
            float a0 = 0.f, a1 = 0.f, a2 = 0.f, a3 = 0.f;
            #pragma unroll
            for (int c = 0; c < 32; ++c) {
                const uint4 hv = *(const uint4*)&xstage[r][c * 4];
                a0 = fdot2(u32_h2(hv.x), wx[4*c+0], a0);
                a1 = fdot2(u32_h2(hv.y), wx[4*c+1], a1);
                a2 = fdot2(u32_h2(hv.z), wx[4*c+2], a2);
                a3 = fdot2(u32_h2(hv.w), wx[4*c+3], a3);
            }
            out[(size_t)(r0 + r) * DHr + col] = ((a0 + a1) + (a2 + a3)) + bxv;
        }
    }
}

// ---------------------------------------------------------------------------
// Kernel B: persistent recurrence. One block per batch element (128 blocks x
// 512 threads). Thread (wave w, lane l): owns columns {p, p+256} with
// p = w*32 + (l&31), k-half s = l>>5 (rows [s*256, s*256+256)).
// Wh kept on-CU: 96 f16 pairs/column/task in VGPRs + 32 pairs in LDS (128 KB).
// h broadcast per step via packed-f16 LDS double buffer; k-halves reduced
// with shfl_xor(32) inside the wave. One __syncthreads per step.
// ---------------------------------------------------------------------------
__global__ __launch_bounds__(512)
void rnn_kernel(const float* __restrict__ h0, const float* __restrict__ Wh,
                const float* __restrict__ bh, float* __restrict__ out)
{
    const int tid   = threadIdx.x;
    const int b     = blockIdx.x;
    const int lane  = tid & 63;
    const int wv    = tid >> 6;
    const int p     = wv * 32 + (lane & 31);
    const int s     = lane >> 5;                  // k-half
    const int mycol = (lane < 32) ? p : (p + 256);

    __shared__ __align__(16) uint32_t hbuf[2][256];   // packed h pairs
    __shared__ uint32_t wldsA[32][512];               // pairs 96..127, col p
    __shared__ uint32_t wldsB[32][512];               // pairs 96..127, col p+256

    half2v wr0[96], wr1[96];
    #pragma unroll
    for (int q = 0; q < 128; ++q) {
        const int k = 2 * (s * 128 + q);
        const float* Wk  = Wh + (size_t)k * DHr;
        const float* Wk1 = Wk + DHr;
        const float a0 = Wk[p],       a1 = Wk1[p];
        const float b0 = Wk[p + 256], b1 = Wk1[p + 256];
        if (q < 96) {
            wr0[q] = __builtin_amdgcn_cvt_pkrtz(a0, a1);
            wr1[q] = __builtin_amdgcn_cvt_pkrtz(b0, b1);
        } else {
            wldsA[q - 96][tid] = pk_u32(a0, a1);
            wldsB[q - 96][tid] = pk_u32(b0, b1);
        }
    }
    const float bhv = bh[mycol];
    float xpv = out[(size_t)b * DHr + mycol];     // xp for t=0 (from kernel A)

    if (tid < 256) {
        const float* h0b = h0 + (size_t)b * DHr + 2 * tid;
        hbuf[0][tid] = pk_u32(h0b[0], h0b[1]);
    }
    __syncthreads();

    #pragma unroll 1
    for (int t = 0; t < Lr; ++t) {
        const uint32_t* hb = &hbuf[t & 1][s * 128];
        float ac00 = 0.f, ac01 = 0.f, ac10 = 0.f, ac11 = 0.f;
        #pragma unroll
        for (int c = 0; c < 24; ++c) {            // 96 register-resident pairs
            const uint4 hv = *(const uint4*)&hb[c * 4];
            ac00 = fdot2(u32_h2(hv.x), wr0[4*c+0], ac00);
            ac10 = fdot2(u32_h2(hv.x), wr1[4*c+0], ac10);
            ac01 = fdot2(u32_h2(hv.y), wr0[4*c+1], ac01);
            ac11 = fdot2(u32_h2(hv.y), wr1[4*c+1], ac11);
            ac00 = fdot2(u32_h2(hv.z), wr0[4*c+2], ac00);
            ac10 = fdot2(u32_h2(hv.z), wr1[4*c+2], ac10);
            ac01 = fdot2(u32_h2(hv.w), wr0[4*c+3], ac01);
            ac11 = fdot2(u32_h2(hv.w), wr1[4*c+3], ac11);
        }
        #pragma unroll
        for (int c = 0; c < 8; ++c) {             // 32 LDS-resident pairs
            const uint4 hv = *(const uint4*)&hb[96 + c * 4];
            const uint32_t hw[4] = {hv.x, hv.y, hv.z, hv.w};
            #pragma unroll
            for (int j = 0; j < 4; ++j) {
                const int q = 4 * c + j;
                const half2v xv = u32_h2(hw[j]);
                const half2v wa = u32_h2(wldsA[q][tid]);
                const half2v wb = u32_h2(wldsB[q][tid]);
                if (j & 1) { ac01 = fdot2(xv, wa, ac01); ac11 = fdot2(xv, wb, ac11); }
                else       { ac00 = fdot2(xv, wa, ac00); ac10 = fdot2(xv, wb, ac10); }
            }
        }
        const float sA = ac00 + ac01;
        const float sB = ac10 + ac11;
        const float rA = sA + __shfl_xor(sA, 32, 64);
        const float rB = sB + __shfl_xor(sB, 32, 64);
        const float sum = (lane < 32) ? rA : rB;

        const float svv = sum + xpv + bhv;
        const float e   = __expf(2.f * svv);
        const float h   = 1.f - 2.f * __builtin_amdgcn_rcpf(e + 1.f);

        out[(size_t)(t * Br + b) * DHr + mycol] = h;
        if (t + 1 < Lr)
            xpv = out[(size_t)((t + 1) * Br + b) * DHr + mycol];  // prefetch xp

        const float hx = __shfl_xor(h, 1, 64);
        if (!(lane & 1))
            hbuf[(t + 1) & 1][mycol >> 1] = pk_u32(h, hx);
        __syncthreads();
    }
}

extern "C" void kernel_launch(void* const* d_in, const int* in_sizes, int n_in,
                              void* d_out, int out_size, void* d_ws, size_t ws_size,
                              hipStream_t stream) {
    (void)in_sizes; (void)n_in; (void)d_ws; (void)ws_size; (void)out_size;
    const float* x  = (const float*)d_in[0];
    const float* h0 = (const float*)d_in[1];
    const float* Wx = (const float*)d_in[2];
    const float* bx = (const float*)d_in[3];
    const float* Wh = (const float*)d_in[4];
    const float* bh = (const float*)d_in[5];
    float* out = (float*)d_out;

    dim3 gA(256, 2), bA(256);
    xp_kernel<<<gA, bA, 0, stream>>>(x, Wx, bx, out);

    dim3 gB(128), bB(512);
    rnn_kernel<<<gB, bB, 0, stream>>>(h0, Wh, bh, out);
}

// Round 9
// 994.747 us; speedup vs baseline: 1.3724x; 1.3724x over previous
//
#include <hip/hip_runtime.h>
#include <stdint.h>

typedef __fp16 half2v __attribute__((ext_vector_type(2)));
typedef __fp16 half8v __attribute__((ext_vector_type(8)));
typedef float floatx4 __attribute__((ext_vector_type(4)));

#define Lr   512
#define Br   128
#define DINr 256
#define DHr  512

__device__ __forceinline__ float fdot2(half2v a, half2v b, float c) {
    return __builtin_amdgcn_fdot2(a, b, c, false);
}
__device__ __forceinline__ uint32_t pk_u32(float lo, float hi) {
    half2v h = __builtin_amdgcn_cvt_pkrtz(lo, hi);
    return __builtin_bit_cast(uint32_t, h);
}
__device__ __forceinline__ half2v u32_h2(uint32_t u) {
    return __builtin_bit_cast(half2v, u);
}

// ---------------------------------------------------------------------------
// Kernel W: convert Wx (f32 [256][512]) into MFMA-B-fragment-ordered f16 in
// d_ws. Fragment layout for mfma_f32_16x16x32_f16, B[k][n]:
//   lane l: col r = l&15, group g = l>>4; element j=0..7 covers k = 32s+8g+j.
// BT half-index: (((nt*8 + s)*4 + g)*16 + r)*8 + j   (nt = n>>4, r = n&15)
// ---------------------------------------------------------------------------
__global__ __launch_bounds__(512)
void wxcvt_kernel(const float* __restrict__ Wx, __fp16* __restrict__ bt)
{
    const int gid = blockIdx.x * 512 + threadIdx.x;   // 256 blocks -> 131072
    const int k = gid >> 9;
    const int n = gid & 511;
    const int s = k >> 5, g = (k >> 3) & 3, j = k & 7;
    const int nt = n >> 4, r = n & 15;
    const int idx = ((((nt * 8 + s) * 4 + g) * 16 + r) * 8) + j;
    bt[idx] = (__fp16)Wx[gid];
}

// ---------------------------------------------------------------------------
// Kernel A: xp = x @ Wx + bx via f16 MFMA 16x16x32, written into d_out.
// Grid 512 blocks x 512 thr (8 waves). Block = 128 rows; wave w = 16 rows.
// A-frags (x rows, f32->f16) preloaded in regs; B-frags coalesced from bt.
// C layout (verified m89): col = lane&15, row = (lane>>4)*4 + reg.
// ---------------------------------------------------------------------------
__global__ __launch_bounds__(512)
void xp_mfma_kernel(const float* __restrict__ x, const __fp16* __restrict__ bt,
                    const float* __restrict__ bx, float* __restrict__ out)
{
    const int tid  = threadIdx.x;
    const int w    = tid >> 6;
    const int lane = tid & 63;
    const int g    = lane >> 4;
    const int r    = lane & 15;
    const int m0   = blockIdx.x * 128 + w * 16;

    const float* xrow = x + (size_t)(m0 + r) * DINr;
    half8v af[8];
    #pragma unroll
    for (int s = 0; s < 8; ++s) {
        const float4 u = *(const float4*)(xrow + 32 * s + 8 * g);
        const float4 v = *(const float4*)(xrow + 32 * s + 8 * g + 4);
        half8v a;
        a[0] = (__fp16)u.x; a[1] = (__fp16)u.y; a[2] = (__fp16)u.z; a[3] = (__fp16)u.w;
        a[4] = (__fp16)v.x; a[5] = (__fp16)v.y; a[6] = (__fp16)v.z; a[7] = (__fp16)v.w;
        af[s] = a;
    }

    const half8v* bt8 = (const half8v*)bt;

    #pragma unroll 4
    for (int nt = 0; nt < 32; ++nt) {
        floatx4 acc = {0.f, 0.f, 0.f, 0.f};
        #pragma unroll
        for (int s = 0; s < 8; ++s) {
            const half8v bf = bt8[((nt * 8 + s) * 4 + g) * 16 + r];
            acc = __builtin_amdgcn_mfma_f32_16x16x32_f16(af[s], bf, acc, 0, 0, 0);
        }
        const float bxv = bx[nt * 16 + r];
        #pragma unroll
        for (int q = 0; q < 4; ++q) {
            out[(size_t)(m0 + 4 * g + q) * DHr + nt * 16 + r] = acc[q] + bxv;
        }
    }
}

// ---------------------------------------------------------------------------
// Kernel B: persistent recurrence. One block per batch element (128 blocks x
// 512 threads). Thread (wave w, lane l): owns columns {p, p+256} with
// p = w*32 + (l&31), k-half s = l>>5 (rows [s*256, s*256+256)).
// Wh on-CU: 96 f16 pairs/column/task in VGPRs + 32 pairs in LDS stored as
// uint4-per-thread ([8][512] uint4) so weight reads are ds_read_b128.
// h broadcast per step via packed-f16 LDS double buffer; k-halves reduced
// with shfl_xor(32). One __syncthreads per step.
// ---------------------------------------------------------------------------
__global__ __launch_bounds__(512)
void rnn_kernel(const float* __restrict__ h0, const float* __restrict__ Wh,
                const float* __restrict__ bh, float* __restrict__ out)
{
    const int tid   = threadIdx.x;
    const int b     = blockIdx.x;
    const int lane  = tid & 63;
    const int wv    = tid >> 6;
    const int p     = wv * 32 + (lane & 31);
    const int s     = lane >> 5;                  // k-half
    const int mycol = (lane < 32) ? p : (p + 256);

    __shared__ __align__(16) uint32_t hbuf[2][256];   // packed h pairs
    __shared__ __align__(16) uint4 wldsA2[8][512];    // pairs 96..127, col p
    __shared__ __align__(16) uint4 wldsB2[8][512];    // pairs 96..127, col p+256

    half2v wr0[96], wr1[96];
    #pragma unroll
    for (int q = 0; q < 96; ++q) {
        const int k = 2 * (s * 128 + q);
        const float* Wk  = Wh + (size_t)k * DHr;
        const float* Wk1 = Wk + DHr;
        wr0[q] = __builtin_amdgcn_cvt_pkrtz(Wk[p],       Wk1[p]);
        wr1[q] = __builtin_amdgcn_cvt_pkrtz(Wk[p + 256], Wk1[p + 256]);
    }
    #pragma unroll
    for (int c = 0; c < 8; ++c) {
        uint4 qa, qb;
        uint32_t* qaw = (uint32_t*)&qa;
        uint32_t* qbw = (uint32_t*)&qb;
        #pragma unroll
        for (int j = 0; j < 4; ++j) {
            const int q = 96 + 4 * c + j;
            const int k = 2 * (s * 128 + q);
            const float* Wk  = Wh + (size_t)k * DHr;
            const float* Wk1 = Wk + DHr;
            qaw[j] = pk_u32(Wk[p],       Wk1[p]);
            qbw[j] = pk_u32(Wk[p + 256], Wk1[p + 256]);
        }
        wldsA2[c][tid] = qa;
        wldsB2[c][tid] = qb;
    }
    const float bhv = bh[mycol];
    float xpv = out[(size_t)b * DHr + mycol];     // xp for t=0 (from kernel A)

    if (tid < 256) {
        const float* h0b = h0 + (size_t)b * DHr + 2 * tid;
        hbuf[0][tid] = pk_u32(h0b[0], h0b[1]);
    }
    __syncthreads();

    #pragma unroll 1
    for (int t = 0; t < Lr; ++t) {
        const uint32_t* hb = &hbuf[t & 1][s * 128];
        float ac00 = 0.f, ac01 = 0.f, ac10 = 0.f, ac11 = 0.f;
        #pragma unroll
        for (int c = 0; c < 24; ++c) {            // 96 register-resident pairs
            const uint4 hv = *(const uint4*)&hb[c * 4];
            ac00 = fdot2(u32_h2(hv.x), wr0[4*c+0], ac00);
            ac10 = fdot2(u32_h2(hv.x), wr1[4*c+0], ac10);
            ac01 = fdot2(u32_h2(hv.y), wr0[4*c+1], ac01);
            ac11 = fdot2(u32_h2(hv.y), wr1[4*c+1], ac11);
            ac00 = fdot2(u32_h2(hv.z), wr0[4*c+2], ac00);
            ac10 = fdot2(u32_h2(hv.z), wr1[4*c+2], ac10);
            ac01 = fdot2(u32_h2(hv.w), wr0[4*c+3], ac01);
            ac11 = fdot2(u32_h2(hv.w), wr1[4*c+3], ac11);
        }
        #pragma unroll
        for (int c = 0; c < 8; ++c) {             // 32 LDS-resident pairs (b128)
            const uint4 hv = *(const uint4*)&hb[96 + c * 4];
            const uint4 wa = wldsA2[c][tid];
            const uint4 wb = wldsB2[c][tid];
            ac00 = fdot2(u32_h2(hv.x), u32_h2(wa.x), ac00);
            ac10 = fdot2(u32_h2(hv.x), u32_h2(wb.x), ac10);
            ac01 = fdot2(u32_h2(hv.y), u32_h2(wa.y), ac01);
            ac11 = fdot2(u32_h2(hv.y), u32_h2(wb.y), ac11);
            ac00 = fdot2(u32_h2(hv.z), u32_h2(wa.z), ac00);
            ac10 = fdot2(u32_h2(hv.z), u32_h2(wb.z), ac10);
            ac01 = fdot2(u32_h2(hv.w), u32_h2(wa.w), ac01);
            ac11 = fdot2(u32_h2(hv.w), u32_h2(wb.w), ac11);
        }
        const float sA = ac00 + ac01;
        const float sB = ac10 + ac11;
        const float rA = sA + __shfl_xor(sA, 32, 64);
        const float rB = sB + __shfl_xor(sB, 32, 64);
        const float sum = (lane < 32) ? rA : rB;

        const float svv = sum + xpv + bhv;
        const float e   = __expf(2.f * svv);
        const float h   = 1.f - 2.f * __builtin_amdgcn_rcpf(e + 1.f);

        out[(size_t)(t * Br + b) * DHr + mycol] = h;
        if (t + 1 < Lr)
            xpv = out[(size_t)((t + 1) * Br + b) * DHr + mycol];  // prefetch xp

        const float hx = __shfl_xor(h, 1, 64);
        if (!(lane & 1))
            hbuf[(t + 1) & 1][mycol >> 1] = pk_u32(h, hx);
        __syncthreads();
    }
}

extern "C" void kernel_launch(void* const* d_in, const int* in_sizes, int n_in,
                              void* d_out, int out_size, void* d_ws, size_t ws_size,
                              hipStream_t stream) {
    (void)in_sizes; (void)n_in; (void)ws_size; (void)out_size;
    const float* x  = (const float*)d_in[0];
    const float* h0 = (const float*)d_in[1];
    const float* Wx = (const float*)d_in[2];
    const float* bx = (const float*)d_in[3];
    const float* Wh = (const float*)d_in[4];
    const float* bh = (const float*)d_in[5];
    float* out  = (float*)d_out;
    __fp16* bt  = (__fp16*)d_ws;   // 131072 * 2B = 256 KB of workspace

    wxcvt_kernel<<<dim3(256), dim3(512), 0, stream>>>(Wx, bt);
    xp_mfma_kernel<<<dim3(512), dim3(512), 0, stream>>>(x, bt, bx, out);
    rnn_kernel<<<dim3(128), dim3(512), 0, stream>>>(h0, Wh, bh, out);
}